// Round 4
// baseline (1288.846 us; speedup 1.0000x reference)
//
#include <hip/hip_runtime.h>

// 3-layer LSTM (T=1024,B=512,F=32,H1=32,H2=8,H3=8) + locked dropout.
// One 64-lane wave per batch element (512 blocks). Weights in VGPRs, h-state
// via LDS, masks folded into next layer's weights / output store.
//
// R4 change: STAGE-SKEWED SOFTWARE PIPELINE. R3 showed ~2266 cyc/step with
// only ~540 cyc of VALU issue -> dependency-latency-bound, layers serialized.
// Iteration i now computes L1(i+2), L2(i+1), L3(i): all three stages read
// only previous-iteration LDS state (h1/h2 double-buffered by parity), so
// they are independent -> 3-way ILP hides LDS-read + FMA-chain latency.
// x is prefetched 4 timesteps ahead (4-slot LDS ring) to cover HBM latency.
// No barriers at all: single wave per block, LDS ops in order, true aliasing
// through the parity buffers enforces the cross-iteration ordering.

constexpr int T = 1024, B = 512, F = 32;
constexpr int H1 = 32, H2 = 8, H3 = 8;

#if __has_builtin(__builtin_amdgcn_rcpf)
#define RCPF(x) __builtin_amdgcn_rcpf(x)
#else
#define RCPF(x) (1.0f / (x))
#endif
#if __has_builtin(__builtin_amdgcn_exp2f)
#define EXP2F(x) __builtin_amdgcn_exp2f(x)
#else
#define EXP2F(x) exp2f(x)
#endif

#define SIG_CM (-1.4426950408889634f)

// unified activation: sigmoid (cm=-log2e, ka=1, kb=0) / tanh (cm=-2log2e, ka=2, kb=-1)
__device__ __forceinline__ float act_f(float v, float cm, float ka, float kb) {
    return fmaf(ka, RCPF(1.0f + EXP2F(v * cm)), kb);
}
__device__ __forceinline__ float tanh_fast(float v) {
    return fmaf(2.0f, RCPF(1.0f + EXP2F(v * (2.0f * SIG_CM))), -1.0f);
}

// macro params avoid float4 member names x/y/z/w (R1 lesson)
#define FMA4(ACC, WARR, VEC, BASE)                                             \
    ACC = fmaf(WARR[(BASE) + 0], VEC.x, ACC);                                  \
    ACC = fmaf(WARR[(BASE) + 1], VEC.y, ACC);                                  \
    ACC = fmaf(WARR[(BASE) + 2], VEC.z, ACC);                                  \
    ACC = fmaf(WARR[(BASE) + 3], VEC.w, ACC);

__global__ __launch_bounds__(64, 1) void lstm3_kernel(
    const float* __restrict__ x,
    const float* __restrict__ Wih1, const float* __restrict__ Whh1,
    const float* __restrict__ bih1, const float* __restrict__ bhh1,
    const float* __restrict__ Wih2, const float* __restrict__ Whh2,
    const float* __restrict__ bih2, const float* __restrict__ bhh2,
    const float* __restrict__ Wih3, const float* __restrict__ Whh3,
    const float* __restrict__ bih3, const float* __restrict__ bhh3,
    const float* __restrict__ mask1, const float* __restrict__ mask2,
    const float* __restrict__ mask3,
    float* __restrict__ out)
{
    const int lane = threadIdx.x;
    const int b = blockIdx.x;

    __shared__ __align__(16) float sh_x[4][F];     // 4-slot x ring (prefetch dist 4)
    __shared__ __align__(16) float sh_h1[2][H1];   // parity delay line
    __shared__ __align__(16) float sh_h2[2][H2];   // parity delay line
    __shared__ __align__(16) float sh_h3[H3];

    // ---------------- weight / bias / mask setup (registers) ----------------
    const int r0 = lane;
    const int r1 = lane + 64;
    float wi1a[F], wh1a[H1], wi1b[F], wh1b[H1];
#pragma unroll
    for (int k = 0; k < F; ++k) {
        wi1a[k] = Wih1[r0 * F + k];
        wi1b[k] = Wih1[r1 * F + k];
    }
#pragma unroll
    for (int k = 0; k < H1; ++k) {
        wh1a[k] = Whh1[r0 * H1 + k];
        wh1b[k] = Whh1[r1 * H1 + k];
    }
    const float bias0 = bih1[r0] + bhh1[r0];
    const float bias1 = bih1[r1] + bhh1[r1];
    const float cm1b = (lane < 32) ? 2.0f * SIG_CM : SIG_CM;
    const float ka1b = (lane < 32) ? 2.0f : 1.0f;
    const float kb1b = (lane < 32) ? -1.0f : 0.0f;

    const int r2 = lane & 31;
    float wi2[H1], wh2[H2];
#pragma unroll
    for (int k = 0; k < H1; ++k) wi2[k] = Wih2[r2 * H1 + k] * mask1[b * H1 + k];
#pragma unroll
    for (int k = 0; k < H2; ++k) wh2[k] = Whh2[r2 * H2 + k];
    const float bias2 = bih2[r2] + bhh2[r2];
    const int sec2 = r2 >> 3;
    const float cm2 = (sec2 == 2) ? 2.0f * SIG_CM : SIG_CM;
    const float ka2 = (sec2 == 2) ? 2.0f : 1.0f;
    const float kb2 = (sec2 == 2) ? -1.0f : 0.0f;

    const int r3 = lane & 31;
    float wi3[H2], wh3[H3];
#pragma unroll
    for (int k = 0; k < H2; ++k) wi3[k] = Wih3[r3 * H2 + k] * mask2[b * H2 + k];
#pragma unroll
    for (int k = 0; k < H3; ++k) wh3[k] = Whh3[r3 * H3 + k];
    const float bias3 = bih3[r3] + bhh3[r3];
    const int sec3 = r3 >> 3;
    const float cm3 = (sec3 == 2) ? 2.0f * SIG_CM : SIG_CM;
    const float ka3 = (sec3 == 2) ? 2.0f : 1.0f;
    const float kb3 = (sec3 == 2) ? -1.0f : 0.0f;

    const float m3 = mask3[b * H3 + (lane & 7)];

    // ---------------- state init ----------------
    float c1 = 0.f, c2 = 0.f, c3 = 0.f;
    if (lane < F) {
        sh_x[0][lane] = x[0 * (B * F) + b * F + lane];
        sh_x[1][lane] = x[1 * (B * F) + b * F + lane];
        sh_x[2][lane] = x[2 * (B * F) + b * F + lane];
        sh_x[3][lane] = x[3 * (B * F) + b * F + lane];
    }
    if (lane < H1) { sh_h1[0][lane] = 0.f; sh_h1[1][lane] = 0.f; }
    if (lane < H2) { sh_h2[0][lane] = 0.f; sh_h2[1][lane] = 0.f; }
    if (lane < H3) sh_h3[lane] = 0.f;

    const int j = lane & 7;

    auto xFetch = [&](int t) -> float {
        const int tn = (t < T) ? t : (T - 1);  // clamped redundant load, branchless
        return (lane < F) ? x[tn * (B * F) + b * F + lane] : 0.f;
    };
    auto xStore = [&](int t, float v) {
        if (lane < F) sh_x[t & 3][lane] = v;
    };

    // L1(t): reads sh_x[t&3], sh_h1[par^1] (=h1(t-1)); writes sh_h1[par]
    auto stageL1 = [&](int t) {
        const int par = t & 1;
        const float4* xp = (const float4*)sh_x[t & 3];
        const float4* hp = (const float4*)sh_h1[par ^ 1];
        float a0xA = 0.f, a0hA = 0.f, a1xA = 0.f, a1hA = 0.f;
        float a0xB = 0.f, a0hB = 0.f, a1xB = 0.f, a1hB = 0.f;
#pragma unroll
        for (int q = 0; q < 4; ++q) {
            float4 xv = xp[q], hv = hp[q];
            FMA4(a0xA, wi1a, xv, 4 * q);
            FMA4(a0hA, wh1a, hv, 4 * q);
            FMA4(a1xA, wi1b, xv, 4 * q);
            FMA4(a1hA, wh1b, hv, 4 * q);
        }
#pragma unroll
        for (int q = 4; q < 8; ++q) {
            float4 xv = xp[q], hv = hp[q];
            FMA4(a0xB, wi1a, xv, 4 * q);
            FMA4(a0hB, wh1a, hv, 4 * q);
            FMA4(a1xB, wi1b, xv, 4 * q);
            FMA4(a1hB, wh1b, hv, 4 * q);
        }
        const float a0 = bias0 + (a0xA + a0hA) + (a0xB + a0hB);
        const float a1 = bias1 + (a1xA + a1hA) + (a1xB + a1hB);
        const float g0 = act_f(a0, SIG_CM, 1.0f, 0.0f);  // i (lanes<32) / f (>=32)
        const float g1 = act_f(a1, cm1b, ka1b, kb1b);    // g (lanes<32) / o (>=32)
        const float f_ = __shfl_xor(g0, 32);
        const float o_ = __shfl_xor(g1, 32);
        c1 = fmaf(f_, c1, g0 * g1);
        const float h1v = o_ * tanh_fast(c1);
        if (lane < H1) sh_h1[par][lane] = h1v;
    };

    // L2(t): reads sh_h1[par] (=h1(t)), sh_h2[par^1] (=h2(t-1)); writes sh_h2[par]
    auto stageL2 = [&](int t) {
        const int par = t & 1;
        const float4* hp = (const float4*)sh_h1[par];
        const float4* h2p = (const float4*)sh_h2[par ^ 1];
        float a2xA = 0.f, a2xB = 0.f, a2h = 0.f;
#pragma unroll
        for (int q = 0; q < 4; ++q) { float4 hv = hp[q]; FMA4(a2xA, wi2, hv, 4 * q); }
#pragma unroll
        for (int q = 4; q < 8; ++q) { float4 hv = hp[q]; FMA4(a2xB, wi2, hv, 4 * q); }
        float4 v0 = h2p[0], v1 = h2p[1];
        FMA4(a2h, wh2, v0, 0);
        FMA4(a2h, wh2, v1, 4);
        const float a2 = bias2 + a2xA + (a2xB + a2h);
        const float r2v = act_f(a2, cm2, ka2, kb2);
        const float i2 = __shfl(r2v, j);
        const float f2 = __shfl(r2v, j + 8);
        const float g2 = __shfl(r2v, j + 16);
        const float o2 = __shfl(r2v, j + 24);
        c2 = fmaf(f2, c2, i2 * g2);
        const float h2v = o2 * tanh_fast(c2);
        if (lane < H2) sh_h2[par][lane] = h2v;
    };

    // L3(t): reads sh_h2[par] (=h2(t)), sh_h3 (=h3(t-1)); writes sh_h3, out(t)
    auto stageL3 = [&](int t) {
        const int par = t & 1;
        const float4* h2p = (const float4*)sh_h2[par];
        const float4* h3p = (const float4*)sh_h3;
        float a3x = 0.f, a3h = 0.f;
        float4 u0 = h2p[0], u1 = h2p[1];
        FMA4(a3x, wi3, u0, 0);
        FMA4(a3x, wi3, u1, 4);
        float4 w0 = h3p[0], w1 = h3p[1];
        FMA4(a3h, wh3, w0, 0);
        FMA4(a3h, wh3, w1, 4);
        const float a3 = bias3 + a3x + a3h;
        const float r3v = act_f(a3, cm3, ka3, kb3);
        const float i3 = __shfl(r3v, j);
        const float f3 = __shfl(r3v, j + 8);
        const float g3 = __shfl(r3v, j + 16);
        const float o3 = __shfl(r3v, j + 24);
        c3 = fmaf(f3, c3, i3 * g3);
        const float h3v = o3 * tanh_fast(c3);
        if (lane < H3) {
            out[t * (B * H3) + b * H3 + lane] = h3v * m3;
            sh_h3[lane] = h3v;
        }
    };

    // ---------------- pipeline prologue ----------------
    { float xn = xFetch(4); stageL1(0);             xStore(4, xn); }
    { float xn = xFetch(5); stageL1(1); stageL2(0); xStore(5, xn); }

    // ---------------- steady state: L1 two ahead, L2 one ahead ----------------
    for (int i = 0; i <= T - 3; ++i) {
        float xn = xFetch(i + 6);
        stageL1(i + 2);
        stageL2(i + 1);
        stageL3(i);
        xStore(i + 6, xn);  // slot (i+6)&3 == (i+2)&3, already consumed above
    }

    // ---------------- epilogue ----------------
    stageL2(T - 1);
    stageL3(T - 2);
    stageL3(T - 1);
}

extern "C" void kernel_launch(void* const* d_in, const int* in_sizes, int n_in,
                              void* d_out, int out_size, void* d_ws, size_t ws_size,
                              hipStream_t stream) {
    (void)in_sizes; (void)n_in; (void)d_ws; (void)ws_size; (void)out_size;
    const float* x     = (const float*)d_in[0];
    const float* Wih1  = (const float*)d_in[1];
    const float* Whh1  = (const float*)d_in[2];
    const float* bih1  = (const float*)d_in[3];
    const float* bhh1  = (const float*)d_in[4];
    const float* Wih2  = (const float*)d_in[5];
    const float* Whh2  = (const float*)d_in[6];
    const float* bih2  = (const float*)d_in[7];
    const float* bhh2  = (const float*)d_in[8];
    const float* Wih3  = (const float*)d_in[9];
    const float* Whh3  = (const float*)d_in[10];
    const float* bih3  = (const float*)d_in[11];
    const float* bhh3  = (const float*)d_in[12];
    const float* mask1 = (const float*)d_in[13];
    const float* mask2 = (const float*)d_in[14];
    const float* mask3 = (const float*)d_in[15];
    float* out = (float*)d_out;

    lstm3_kernel<<<dim3(B), dim3(64), 0, stream>>>(
        x, Wih1, Whh1, bih1, bhh1, Wih2, Whh2, bih2, bhh2,
        Wih3, Whh3, bih3, bhh3, mask1, mask2, mask3, out);
}